// Round 2
// baseline (1177.947 us; speedup 1.0000x reference)
//
#include <hip/hip_runtime.h>
#include <cstdint>

#define ENC_DEPTH 8
#define RPB 64
#define THREADS 512

typedef __attribute__((ext_vector_type(8))) short bf16x8;
typedef __attribute__((ext_vector_type(4))) float f32x4;

__device__ __forceinline__ unsigned short f2bf(float x) {
    union { float f; unsigned u; } v; v.f = x;
    unsigned r = v.u + 0x7fffu + ((v.u >> 16) & 1u);
    return (unsigned short)(r >> 16);
}
__device__ __forceinline__ float bf2f(unsigned short h) {
    union { unsigned u; float f; } v; v.u = ((unsigned)h) << 16;
    return v.f;
}
__device__ __forceinline__ float clamp01(float x) { return fminf(fmaxf(x, 0.f), 1.f); }

// Three 17408-B LDS regions, stride 136 shorts (68 dw == 4 mod 32: every b128
// lands on disjoint 4-bank groups, 8 lanes/group = minimum cycles, 0 conflict).
//  corners_s: [ray][k*16+f] bf16 (k-major, staged with 2 contiguous b128/thread)
//  feat_s:    [ray][p*16+f] bf16 ; epilogue alias: h1 f32 [64][68]
//  w1t_s:     [col][k]      bf16 ; epilogue alias: W2 f32 [64][68]
//  corners_s epilogue alias: h2 f32 [64][68]
// Total 52224 B -> 3 blocks/CU (24 waves) vs previous 2 (16 waves).
__global__ __launch_bounds__(THREADS, 6) void nbvh_kernel(
    const float* __restrict__ orig, const float* __restrict__ endp,
    const int* __restrict__ hist, const float* __restrict__ nodes_min,
    const float* __restrict__ nodes_extent, const float* __restrict__ emb,
    const float* __restrict__ W1, const float* __restrict__ W2,
    const float* __restrict__ W3, float* __restrict__ out)
{
    __shared__ __align__(16) unsigned short corners_s[RPB * 136];
    __shared__ __align__(16) unsigned short feat_s[RPB * 136];
    __shared__ __align__(16) unsigned short w1t_s[64 * 136];

    const int t = threadIdx.x;
    const int r0 = blockIdx.x * RPB;
    const int wave = t >> 6, lane = t & 63;
    const int ray = t >> 3, kc = t & 7;   // gather / A2 role (8 threads per ray)
    // W1 staging role: col = lane (coalesced 256B global rows), k-group = wave

    // ray origin/end in registers (8-lane broadcast loads, L2)
    const float* opr = orig + (size_t)(r0 + ray) * 3;
    const float* epr = endp + (size_t)(r0 + ray) * 3;
    float oex = opr[0], oey = opr[1], oez = opr[2];
    float eex = epr[0], eey = epr[1], eez = epr[2];

    const int* hrow_g = hist + (size_t)(r0 + ray) * ENC_DEPTH;

    // ---- depth-0 prefetch into registers ----
    int node = hrow_g[0];
    const float4* ep = (const float4*)(emb + ((size_t)node << 7) + (kc << 4));
    float4 pf0 = ep[0], pf1 = ep[1], pf2 = ep[2], pf3 = ep[3];
    float w1p[16];
    #pragma unroll
    for (int j = 0; j < 16; ++j)
        w1p[j] = W1[(size_t)((j >> 3) * 64 + wave * 8 + (j & 7)) * 64 + lane];
    float nm0 = nodes_min[node * 3 + 0], nm1 = nodes_min[node * 3 + 1], nm2 = nodes_min[node * 3 + 2];
    float ex0 = nodes_extent[node * 3 + 0], ex1 = nodes_extent[node * 3 + 1], ex2 = nodes_extent[node * 3 + 2];

    f32x4 acc0 = {0.f, 0.f, 0.f, 0.f};
    f32x4 acc1 = {0.f, 0.f, 0.f, 0.f};
    const int m0 = (wave >> 1) * 16;
    const int n0 = (wave & 1) * 32;

    float nn0 = 0.f, nn1 = 0.f, nn2 = 0.f, en0 = 0.f, en1 = 0.f, en2 = 0.f;

    for (int d = 0; d < ENC_DEPTH; ++d) {
        // ---- stage corners k-major: 2 contiguous ds_write_b128 ----
        {
            float e0 = pf0.x, e1 = pf0.y, e2 = pf0.z, e3 = pf0.w;
            float e4 = pf1.x, e5 = pf1.y, e6 = pf1.z, e7 = pf1.w;
            float e8 = pf2.x, e9 = pf2.y, e10 = pf2.z, e11 = pf2.w;
            float e12 = pf3.x, e13 = pf3.y, e14 = pf3.z, e15 = pf3.w;
            bf16x8 c0, c1;
            c0[0] = (short)f2bf(e0);  c0[1] = (short)f2bf(e1);
            c0[2] = (short)f2bf(e2);  c0[3] = (short)f2bf(e3);
            c0[4] = (short)f2bf(e4);  c0[5] = (short)f2bf(e5);
            c0[6] = (short)f2bf(e6);  c0[7] = (short)f2bf(e7);
            c1[0] = (short)f2bf(e8);  c1[1] = (short)f2bf(e9);
            c1[2] = (short)f2bf(e10); c1[3] = (short)f2bf(e11);
            c1[4] = (short)f2bf(e12); c1[5] = (short)f2bf(e13);
            c1[6] = (short)f2bf(e14); c1[7] = (short)f2bf(e15);
            unsigned short* cb = corners_s + ray * 136 + (kc << 4);
            *(bf16x8*)cb = c0;
            *(bf16x8*)(cb + 8) = c1;
        }
        // ---- stage W1 column-slices: 2 contiguous ds_write_b128 (free transpose) ----
        {
            bf16x8 wv0, wv1;
            #pragma unroll
            for (int j = 0; j < 8; ++j) {
                wv0[j] = (short)f2bf(w1p[j]);
                wv1[j] = (short)f2bf(w1p[8 + j]);
            }
            unsigned short* wb = w1t_s + lane * 136 + wave * 8;
            *(bf16x8*)wb = wv0;          // k = wave*8 + j
            *(bf16x8*)(wb + 64) = wv1;   // k = 64 + wave*8 + j
        }
        // ---- issue depth d+1 prefetch (stays in flight across barriers) ----
        if (d < ENC_DEPTH - 1) {
            int node1 = hrow_g[d + 1];
            const float4* ep2 = (const float4*)(emb + ((size_t)node1 << 7) + (kc << 4));
            pf0 = ep2[0]; pf1 = ep2[1]; pf2 = ep2[2]; pf3 = ep2[3];
            const float* w1b = W1 + (size_t)(d + 1) * 128 * 64;
            #pragma unroll
            for (int j = 0; j < 16; ++j)
                w1p[j] = w1b[(size_t)((j >> 3) * 64 + wave * 8 + (j & 7)) * 64 + lane];
            nn0 = nodes_min[node1 * 3 + 0]; nn1 = nodes_min[node1 * 3 + 1]; nn2 = nodes_min[node1 * 3 + 2];
            en0 = nodes_extent[node1 * 3 + 0]; en1 = nodes_extent[node1 * 3 + 1]; en2 = nodes_extent[node1 * 3 + 2];
        }

        // ---- A2: trilinear weights, k-outer accumulate, feat write ----
        // corners RAW is same-wave (8 threads of a ray); compiler lgkm waits suffice.
        {
            float rx = __builtin_amdgcn_rcpf(ex0);
            float ry = __builtin_amdgcn_rcpf(ex1);
            float rz = __builtin_amdgcn_rcpf(ex2);
            float po0 = clamp01((oex - nm0) * rx);
            float po1 = clamp01((oey - nm1) * ry);
            float po2 = clamp01((oez - nm2) * rz);
            float pe0 = clamp01((eex - nm0) * rx);
            float pe1 = clamp01((eey - nm1) * ry);
            float pe2 = clamp01((eez - nm2) * rz);
            float tt = (float)kc * (1.0f / 7.0f);
            float x = po0 + (pe0 - po0) * tt;
            float y = po1 + (pe1 - po1) * tt;
            float z = po2 + (pe2 - po2) * tt;
            float ox = 1.f - x, oy = 1.f - y, oz = 1.f - z;
            float w[8];
            w[0] = ox * oy * oz;  w[1] = x * oy * oz;
            w[2] = ox * y * oz;   w[3] = ox * oy * z;
            w[4] = x * oy * z;    w[5] = ox * y * z;
            w[6] = x * y * oz;    w[7] = x * y * z;
            float facc[16];
            #pragma unroll
            for (int f = 0; f < 16; ++f) facc[f] = 0.f;
            const unsigned short* cbase = corners_s + ray * 136;
            #pragma unroll
            for (int k = 0; k < 8; ++k) {
                bf16x8 cv0 = *(const bf16x8*)(cbase + (k << 4));
                bf16x8 cv1 = *(const bf16x8*)(cbase + (k << 4) + 8);
                #pragma unroll
                for (int f = 0; f < 8; ++f) {
                    facc[f]     = fmaf(w[k], bf2f((unsigned short)cv0[f]), facc[f]);
                    facc[f + 8] = fmaf(w[k], bf2f((unsigned short)cv1[f]), facc[f + 8]);
                }
            }
            bf16x8 f0v, f1v;
            #pragma unroll
            for (int f = 0; f < 8; ++f) {
                f0v[f] = (short)f2bf(facc[f]);
                f1v[f] = (short)f2bf(facc[f + 8]);
            }
            unsigned short* fb = feat_s + ray * 136 + (kc << 4);
            *(bf16x8*)fb = f0v;
            *(bf16x8*)(fb + 8) = f1v;
        }

        asm volatile("s_waitcnt lgkmcnt(0)" ::: "memory");
        __builtin_amdgcn_s_barrier();
        asm volatile("" ::: "memory");

        // ---- MFMA: accumulate this K=128 chunk ----
        {
            int q = lane >> 4, c = lane & 15;
            #pragma unroll
            for (int kk = 0; kk < 4; ++kk) {
                int koff = kk * 32 + q * 8;
                bf16x8 af = *(const bf16x8*)(feat_s + (m0 + c) * 136 + koff);
                bf16x8 b0 = *(const bf16x8*)(w1t_s + (n0 + c) * 136 + koff);
                bf16x8 b1 = *(const bf16x8*)(w1t_s + (n0 + 16 + c) * 136 + koff);
                acc0 = __builtin_amdgcn_mfma_f32_16x16x32_bf16(af, b0, acc0, 0, 0, 0);
                acc1 = __builtin_amdgcn_mfma_f32_16x16x32_bf16(af, b1, acc1, 0, 0, 0);
            }
        }

        asm volatile("s_waitcnt lgkmcnt(0)" ::: "memory");
        __builtin_amdgcn_s_barrier();
        asm volatile("" ::: "memory");

        nm0 = nn0; nm1 = nn1; nm2 = nn2;
        ex0 = en0; ex1 = en1; ex2 = en2;
    }

    // ---- h1 = relu(GEMM1) -> feat region as f32, stride 68 dw (16B aligned rows) ----
    float* h1s = (float*)feat_s;
    {
        int colb = lane & 15, rq = (lane >> 4) << 2;
        #pragma unroll
        for (int r = 0; r < 4; ++r) {
            h1s[(m0 + rq + r) * 68 + n0 + colb]      = fmaxf(acc0[r], 0.f);
            h1s[(m0 + rq + r) * 68 + n0 + 16 + colb] = fmaxf(acc1[r], 0.f);
        }
    }
    // ---- stage W2 (f32) into w1t region, stride 68 ----
    float* w2s = (float*)w1t_s;
    {
        int row = t >> 3, cg = (t & 7) << 3;
        const float4* wr = (const float4*)(W2 + (row << 6) + cg);
        float4 wa = wr[0], wb = wr[1];
        *(float4*)(w2s + row * 68 + cg) = wa;
        *(float4*)(w2s + row * 68 + cg + 4) = wb;
    }
    asm volatile("s_waitcnt lgkmcnt(0)" ::: "memory");
    __builtin_amdgcn_s_barrier();
    asm volatile("" ::: "memory");

    // ---- GEMM2: h2 = relu(h1 @ W2), fp32 VALU, all-LDS operands ----
    float* h2s = (float*)corners_s;   // stride 68 dw
    {
        int jg = (t & 7) << 3;
        float s0 = 0.f, s1 = 0.f, s2 = 0.f, s3 = 0.f, s4 = 0.f, s5 = 0.f, s6 = 0.f, s7 = 0.f;
        const float* hr = h1s + ray * 68;
        #pragma unroll
        for (int i4 = 0; i4 < 16; ++i4) {
            float4 hv = *(const float4*)(hr + (i4 << 2));
            const float* w0p = w2s + (i4 * 4 + 0) * 68 + jg;
            const float* w1q = w2s + (i4 * 4 + 1) * 68 + jg;
            const float* w2q = w2s + (i4 * 4 + 2) * 68 + jg;
            const float* w3q = w2s + (i4 * 4 + 3) * 68 + jg;
            float4 a0 = *(const float4*)w0p, b0 = *(const float4*)(w0p + 4);
            float4 a1 = *(const float4*)w1q, b1 = *(const float4*)(w1q + 4);
            float4 a2 = *(const float4*)w2q, b2 = *(const float4*)(w2q + 4);
            float4 a3 = *(const float4*)w3q, b3 = *(const float4*)(w3q + 4);
            s0 = fmaf(hv.x, a0.x, s0); s1 = fmaf(hv.x, a0.y, s1);
            s2 = fmaf(hv.x, a0.z, s2); s3 = fmaf(hv.x, a0.w, s3);
            s4 = fmaf(hv.x, b0.x, s4); s5 = fmaf(hv.x, b0.y, s5);
            s6 = fmaf(hv.x, b0.z, s6); s7 = fmaf(hv.x, b0.w, s7);
            s0 = fmaf(hv.y, a1.x, s0); s1 = fmaf(hv.y, a1.y, s1);
            s2 = fmaf(hv.y, a1.z, s2); s3 = fmaf(hv.y, a1.w, s3);
            s4 = fmaf(hv.y, b1.x, s4); s5 = fmaf(hv.y, b1.y, s5);
            s6 = fmaf(hv.y, b1.z, s6); s7 = fmaf(hv.y, b1.w, s7);
            s0 = fmaf(hv.z, a2.x, s0); s1 = fmaf(hv.z, a2.y, s1);
            s2 = fmaf(hv.z, a2.z, s2); s3 = fmaf(hv.z, a2.w, s3);
            s4 = fmaf(hv.z, b2.x, s4); s5 = fmaf(hv.z, b2.y, s5);
            s6 = fmaf(hv.z, b2.z, s6); s7 = fmaf(hv.z, b2.w, s7);
            s0 = fmaf(hv.w, a3.x, s0); s1 = fmaf(hv.w, a3.y, s1);
            s2 = fmaf(hv.w, a3.z, s2); s3 = fmaf(hv.w, a3.w, s3);
            s4 = fmaf(hv.w, b3.x, s4); s5 = fmaf(hv.w, b3.y, s5);
            s6 = fmaf(hv.w, b3.z, s6); s7 = fmaf(hv.w, b3.w, s7);
        }
        float4 r1; r1.x = fmaxf(s0, 0.f); r1.y = fmaxf(s1, 0.f); r1.z = fmaxf(s2, 0.f); r1.w = fmaxf(s3, 0.f);
        float4 r2; r2.x = fmaxf(s4, 0.f); r2.y = fmaxf(s5, 0.f); r2.z = fmaxf(s6, 0.f); r2.w = fmaxf(s7, 0.f);
        float* hb = h2s + ray * 68 + jg;
        *(float4*)hb = r1;
        *(float4*)(hb + 4) = r2;
    }
    asm volatile("s_waitcnt lgkmcnt(0)" ::: "memory");
    __builtin_amdgcn_s_barrier();
    asm volatile("" ::: "memory");

    // ---- GEMM3 + output ----
    if (t < 128) {
        int ray2 = t >> 1, c = t & 1;
        const float* hr = h2s + ray2 * 68;
        float a = 0.f;
        #pragma unroll
        for (int i4 = 0; i4 < 16; ++i4) {
            float4 hv = *(const float4*)(hr + (i4 << 2));
            const float4* w3p = (const float4*)(W3 + (i4 << 3));
            float4 wa = w3p[0], wb = w3p[1];
            if (c == 0) {
                a = fmaf(hv.x, wa.x, a); a = fmaf(hv.y, wa.z, a);
                a = fmaf(hv.z, wb.x, a); a = fmaf(hv.w, wb.z, a);
            } else {
                a = fmaf(hv.x, wa.y, a); a = fmaf(hv.y, wa.w, a);
                a = fmaf(hv.z, wb.y, a); a = fmaf(hv.w, wb.w, a);
            }
        }
        if (c) {
            const float* o2p = orig + (size_t)(r0 + ray2) * 3;
            const float* e2p = endp + (size_t)(r0 + ray2) * 3;
            float dx = e2p[0] - o2p[0], dy = e2p[1] - o2p[1], dz = e2p[2] - o2p[2];
            a *= sqrtf(dx * dx + dy * dy + dz * dz);
        }
        out[((r0 + ray2) << 1) + c] = a;
    }
}

extern "C" void kernel_launch(void* const* d_in, const int* in_sizes, int n_in,
                              void* d_out, int out_size, void* d_ws, size_t ws_size,
                              hipStream_t stream) {
    const float* orig = (const float*)d_in[0];
    const float* endp = (const float*)d_in[1];
    const int*   hist = (const int*)d_in[2];
    const float* nmin = (const float*)d_in[3];
    const float* next = (const float*)d_in[4];
    const float* emb  = (const float*)d_in[5];
    const float* W1   = (const float*)d_in[6];
    const float* W2   = (const float*)d_in[7];
    const float* W3   = (const float*)d_in[8];
    float* out = (float*)d_out;
    const int n_rays = in_sizes[0] / 3;
    dim3 grid(n_rays / RPB);
    nbvh_kernel<<<grid, THREADS, 0, stream>>>(orig, endp, hist, nmin, next,
                                              emb, W1, W2, W3, out);
}

// Round 4
// 520.303 us; speedup vs baseline: 2.2640x; 2.2640x over previous
//
#include <hip/hip_runtime.h>
#include <cstdint>

#define ENC_DEPTH 8
#define RPB 64
#define THREADS 512

typedef __attribute__((ext_vector_type(8))) short bf16x8;
typedef __attribute__((ext_vector_type(4))) float f32x4;

union bf8u { bf16x8 v; unsigned u[4]; };

__device__ __forceinline__ unsigned short f2bf(float x) {
    union { float f; unsigned u; } v; v.f = x;
    unsigned r = v.u + 0x7fffu + ((v.u >> 16) & 1u);
    return (unsigned short)(r >> 16);
}
__device__ __forceinline__ float bf2f(unsigned short h) {
    union { unsigned u; float f; } v; v.u = ((unsigned)h) << 16;
    return v.f;
}
// packed f32x2 -> bf16x2 (RNE, same rounding as f2bf)
__device__ __forceinline__ unsigned cvtpk(float lo, float hi) {
    unsigned r;
    asm volatile("v_cvt_pk_bf16_f32 %0, %1, %2" : "=v"(r) : "v"(lo), "v"(hi));
    return r;
}
__device__ __forceinline__ float clamp01(float x) { return fminf(fmaxf(x, 0.f), 1.f); }

// Pre-pass: W1 f32 [1024][64] row-major -> W1T bf16 [col][k] = [64][1024] (128 KB).
// IN_DIM = 8*8*16 = 1024 (NOT 8192 -- R3's OOB crash).
__global__ void w1t_pre(const float* __restrict__ W1, unsigned short* __restrict__ W1T) {
    int tid = blockIdx.x * 256 + threadIdx.x;      // 8192 threads
    int col = tid >> 7, kb = tid & 127;            // col in [0,64), kb in [0,128)
    const float* src = W1 + (size_t)kb * 512 + col; // W1[(kb*8+j)*64 + col]
    bf8u r;
    #pragma unroll
    for (int j = 0; j < 4; ++j)
        r.u[j] = cvtpk(src[(2 * j) * 64], src[(2 * j + 1) * 64]);
    *(bf16x8*)(W1T + (size_t)col * 1024 + kb * 8) = r.v;
}

// LDS: hist 2048 + 3 x [64][136] bf16 (17408 each) = 54272 B -> 3 blocks/CU fits
// (162816 <= 163840) iff VGPR <= ~84. launch_bounds(512,5) caps at ~102 so the
// compiler is never FORCED to spill (R2 failure mode); if natural alloc <= 84
// the HW gives 6 waves/SIMD = 3 blocks.
template<bool GW>
__global__ __launch_bounds__(THREADS, GW ? 5 : 4) void nbvh_kernel(
    const float* __restrict__ orig, const float* __restrict__ endp,
    const int* __restrict__ hist, const float* __restrict__ nodes_min,
    const float* __restrict__ nodes_extent, const float* __restrict__ emb,
    const float* __restrict__ W1, const unsigned short* __restrict__ W1T,
    const float* __restrict__ W2, const float* __restrict__ W3,
    float* __restrict__ out)
{
    __shared__ int hist_s[RPB * ENC_DEPTH];
    __shared__ __align__(16) unsigned short corners_s[64 * 136];
    __shared__ __align__(16) unsigned short feat_s[64 * 136];
    __shared__ __align__(16) unsigned short w1t_s[64 * 136];

    const int t = threadIdx.x;
    const int r0 = blockIdx.x * RPB;
    const int wave = t >> 6, lane = t & 63;
    const int rayl = t >> 3, kc = t & 7;

    hist_s[t] = hist[r0 * ENC_DEPTH + t];

    const float* opr = orig + (size_t)(r0 + rayl) * 3;
    const float* epr = endp + (size_t)(r0 + rayl) * 3;
    float oex = opr[0], oey = opr[1], oez = opr[2];
    float eex = epr[0], eey = epr[1], eez = epr[2];

    // hist_s written/read within the same wave only
    asm volatile("s_waitcnt lgkmcnt(0)" ::: "memory");

    // ---- depth-0 prefetch ----
    int node = hist_s[rayl << 3];
    const float4* ep0 = (const float4*)(emb + ((size_t)node << 7) + (kc << 4));
    float4 pf0 = ep0[0], pf1 = ep0[1], pf2 = ep0[2], pf3 = ep0[3];
    float nm0 = nodes_min[node * 3], nm1 = nodes_min[node * 3 + 1], nm2 = nodes_min[node * 3 + 2];
    float ex0 = nodes_extent[node * 3], ex1 = nodes_extent[node * 3 + 1], ex2 = nodes_extent[node * 3 + 2];

    f32x4 acc0 = {0.f, 0.f, 0.f, 0.f};
    f32x4 acc1 = {0.f, 0.f, 0.f, 0.f};
    const int m0 = (wave >> 1) * 16;
    const int n0 = (wave & 1) * 32;
    const float tt = (float)kc * (1.0f / 7.0f);

    float nn0 = 0.f, nn1 = 0.f, nn2 = 0.f, en0 = 0.f, en1 = 0.f, en2 = 0.f;

    for (int d = 0; d < ENC_DEPTH; ++d) {
        // ---- (a) issue W1 stage loads first (oldest in vmcnt FIFO, consumed this iter) ----
        bf16x8 wtl0, wtl1;
        float wfa[16];
        if constexpr (GW) {
            const unsigned short* wp = W1T + (size_t)rayl * 1024 + d * 128 + (kc << 4);
            wtl0 = *(const bf16x8*)wp;
            wtl1 = *(const bf16x8*)(wp + 8);
        } else {
            const float* wp = W1 + (size_t)(d * 128 + (kc << 4)) * 64 + rayl;
            #pragma unroll
            for (int j = 0; j < 16; ++j) wfa[j] = wp[j << 6];
        }

        // ---- (b) stage corners from prefetch regs: pk-cvt + 2 ds_write_b128 ----
        {
            bf8u c0, c1;
            c0.u[0] = cvtpk(pf0.x, pf0.y); c0.u[1] = cvtpk(pf0.z, pf0.w);
            c0.u[2] = cvtpk(pf1.x, pf1.y); c0.u[3] = cvtpk(pf1.z, pf1.w);
            c1.u[0] = cvtpk(pf2.x, pf2.y); c1.u[1] = cvtpk(pf2.z, pf2.w);
            c1.u[2] = cvtpk(pf3.x, pf3.y); c1.u[3] = cvtpk(pf3.z, pf3.w);
            unsigned short* cb = corners_s + rayl * 136 + (kc << 4);
            *(bf16x8*)cb = c0.v;
            *(bf16x8*)(cb + 8) = c1.v;
        }

        // ---- (c) issue depth d+1 prefetch (newest in FIFO, consumed next iter) ----
        if (d < ENC_DEPTH - 1) {
            int node1 = hist_s[(rayl << 3) + d + 1];
            const float4* ep2 = (const float4*)(emb + ((size_t)node1 << 7) + (kc << 4));
            pf0 = ep2[0]; pf1 = ep2[1]; pf2 = ep2[2]; pf3 = ep2[3];
            nn0 = nodes_min[node1 * 3]; nn1 = nodes_min[node1 * 3 + 1]; nn2 = nodes_min[node1 * 3 + 2];
            en0 = nodes_extent[node1 * 3]; en1 = nodes_extent[node1 * 3 + 1]; en2 = nodes_extent[node1 * 3 + 2];
        }

        // ---- (d) write W1 chunk to LDS (waits only the oldest vmcnt loads) ----
        if constexpr (GW) {
            unsigned short* wb = w1t_s + rayl * 136 + (kc << 4);
            *(bf16x8*)wb = wtl0;
            *(bf16x8*)(wb + 8) = wtl1;
        } else {
            bf8u a0, a1;
            #pragma unroll
            for (int j = 0; j < 4; ++j) {
                a0.u[j] = cvtpk(wfa[2 * j], wfa[2 * j + 1]);
                a1.u[j] = cvtpk(wfa[8 + 2 * j], wfa[9 + 2 * j]);
            }
            unsigned short* wb = w1t_s + rayl * 136 + (kc << 4);
            *(bf16x8*)wb = a0.v;
            *(bf16x8*)(wb + 8) = a1.v;
        }

        // ---- (e) A2: trilinear weights, two 8-feature passes ----
        {
            float rx = __builtin_amdgcn_rcpf(ex0);
            float ry = __builtin_amdgcn_rcpf(ex1);
            float rz = __builtin_amdgcn_rcpf(ex2);
            float po0 = clamp01((oex - nm0) * rx);
            float po1 = clamp01((oey - nm1) * ry);
            float po2 = clamp01((oez - nm2) * rz);
            float pe0 = clamp01((eex - nm0) * rx);
            float pe1 = clamp01((eey - nm1) * ry);
            float pe2 = clamp01((eez - nm2) * rz);
            float x = po0 + (pe0 - po0) * tt;
            float y = po1 + (pe1 - po1) * tt;
            float z = po2 + (pe2 - po2) * tt;
            float ox = 1.f - x, oy = 1.f - y, oz = 1.f - z;
            float w[8];
            w[0] = ox * oy * oz;  w[1] = x * oy * oz;
            w[2] = ox * y * oz;   w[3] = ox * oy * z;
            w[4] = x * oy * z;    w[5] = ox * y * z;
            w[6] = x * y * oz;    w[7] = x * y * z;

            const unsigned short* cbase = corners_s + rayl * 136;
            bf8u f0v, f1v;
            {   // features 0..7
                float fa[8];
                #pragma unroll
                for (int f = 0; f < 8; ++f) fa[f] = 0.f;
                #pragma unroll
                for (int k = 0; k < 8; ++k) {
                    bf16x8 cv = *(const bf16x8*)(cbase + (k << 4));
                    #pragma unroll
                    for (int f = 0; f < 8; ++f)
                        fa[f] = fmaf(w[k], bf2f((unsigned short)cv[f]), fa[f]);
                }
                #pragma unroll
                for (int j = 0; j < 4; ++j) f0v.u[j] = cvtpk(fa[2 * j], fa[2 * j + 1]);
            }
            {   // features 8..15
                float fb_[8];
                #pragma unroll
                for (int f = 0; f < 8; ++f) fb_[f] = 0.f;
                #pragma unroll
                for (int k = 0; k < 8; ++k) {
                    bf16x8 cv = *(const bf16x8*)(cbase + (k << 4) + 8);
                    #pragma unroll
                    for (int f = 0; f < 8; ++f)
                        fb_[f] = fmaf(w[k], bf2f((unsigned short)cv[f]), fb_[f]);
                }
                #pragma unroll
                for (int j = 0; j < 4; ++j) f1v.u[j] = cvtpk(fb_[2 * j], fb_[2 * j + 1]);
            }
            unsigned short* fbp = feat_s + rayl * 136 + (kc << 4);
            *(bf16x8*)fbp = f0v.v;
            *(bf16x8*)(fbp + 8) = f1v.v;
        }

        asm volatile("s_waitcnt lgkmcnt(0)" ::: "memory");
        __builtin_amdgcn_s_barrier();
        asm volatile("" ::: "memory");

        // ---- MFMA: all-LDS operands (no vmcnt consumption -> prefetch survives) ----
        {
            int q = lane >> 4, c = lane & 15;
            #pragma unroll
            for (int kk = 0; kk < 4; ++kk) {
                int koff = kk * 32 + q * 8;
                bf16x8 af = *(const bf16x8*)(feat_s + (m0 + c) * 136 + koff);
                bf16x8 b0 = *(const bf16x8*)(w1t_s + (n0 + c) * 136 + koff);
                bf16x8 b1 = *(const bf16x8*)(w1t_s + (n0 + 16 + c) * 136 + koff);
                acc0 = __builtin_amdgcn_mfma_f32_16x16x32_bf16(af, b0, acc0, 0, 0, 0);
                acc1 = __builtin_amdgcn_mfma_f32_16x16x32_bf16(af, b1, acc1, 0, 0, 0);
            }
        }

        asm volatile("s_waitcnt lgkmcnt(0)" ::: "memory");
        __builtin_amdgcn_s_barrier();
        asm volatile("" ::: "memory");

        nm0 = nn0; nm1 = nn1; nm2 = nn2;
        ex0 = en0; ex1 = en1; ex2 = en2;
    }

    // ---- h1 = relu(GEMM1) -> feat region, f32 [64][68] ----
    float* h1s = (float*)feat_s;
    {
        int colb = lane & 15, rq = (lane >> 4) << 2;
        #pragma unroll
        for (int r = 0; r < 4; ++r) {
            h1s[(m0 + rq + r) * 68 + n0 + colb]      = fmaxf(acc0[r], 0.f);
            h1s[(m0 + rq + r) * 68 + n0 + 16 + colb] = fmaxf(acc1[r], 0.f);
        }
    }
    // ---- stage W2 -> w1t region, f32 [64][68] ----
    float* w2s = (float*)w1t_s;
    {
        int row = t >> 3, cgr8 = (t & 7) << 3;
        const float4* wr = (const float4*)(W2 + (row << 6) + cgr8);
        float4 wa = wr[0], wbv = wr[1];
        *(float4*)(w2s + row * 68 + cgr8) = wa;
        *(float4*)(w2s + row * 68 + cgr8 + 4) = wbv;
    }
    asm volatile("s_waitcnt lgkmcnt(0)" ::: "memory");
    __builtin_amdgcn_s_barrier();
    asm volatile("" ::: "memory");

    // ---- GEMM2: h2 = relu(h1 @ W2). Thread owns cols [4t',4t'+3] u [32+4t',...] ----
    float* h2s = (float*)corners_s;
    {
        int tp4 = (t & 7) << 2;
        float slo0 = 0.f, slo1 = 0.f, slo2 = 0.f, slo3 = 0.f;
        float shi0 = 0.f, shi1 = 0.f, shi2 = 0.f, shi3 = 0.f;
        const float* hr = h1s + rayl * 68;
        #pragma unroll
        for (int i4 = 0; i4 < 16; ++i4) {
            float4 hv = *(const float4*)(hr + (i4 << 2));
            #pragma unroll
            for (int s = 0; s < 4; ++s) {
                float h = (s == 0) ? hv.x : (s == 1) ? hv.y : (s == 2) ? hv.z : hv.w;
                const float* wrow = w2s + (i4 * 4 + s) * 68;
                float4 wlo = *(const float4*)(wrow + tp4);
                float4 whi = *(const float4*)(wrow + 32 + tp4);
                slo0 = fmaf(h, wlo.x, slo0); slo1 = fmaf(h, wlo.y, slo1);
                slo2 = fmaf(h, wlo.z, slo2); slo3 = fmaf(h, wlo.w, slo3);
                shi0 = fmaf(h, whi.x, shi0); shi1 = fmaf(h, whi.y, shi1);
                shi2 = fmaf(h, whi.z, shi2); shi3 = fmaf(h, whi.w, shi3);
            }
        }
        float4 rlo; rlo.x = fmaxf(slo0, 0.f); rlo.y = fmaxf(slo1, 0.f);
        rlo.z = fmaxf(slo2, 0.f); rlo.w = fmaxf(slo3, 0.f);
        float4 rhi; rhi.x = fmaxf(shi0, 0.f); rhi.y = fmaxf(shi1, 0.f);
        rhi.z = fmaxf(shi2, 0.f); rhi.w = fmaxf(shi3, 0.f);
        *(float4*)(h2s + rayl * 68 + tp4) = rlo;
        *(float4*)(h2s + rayl * 68 + 32 + tp4) = rhi;
    }
    asm volatile("s_waitcnt lgkmcnt(0)" ::: "memory");
    __builtin_amdgcn_s_barrier();
    asm volatile("" ::: "memory");

    // ---- GEMM3 + output ----
    if (t < 128) {
        int ray2 = t >> 1, c = t & 1;
        const float* hr = h2s + ray2 * 68;
        float a = 0.f;
        #pragma unroll
        for (int i4 = 0; i4 < 16; ++i4) {
            float4 hv = *(const float4*)(hr + (i4 << 2));
            const float4* w3p = (const float4*)(W3 + (i4 << 3));
            float4 wa = w3p[0], wbv = w3p[1];
            if (c == 0) {
                a = fmaf(hv.x, wa.x, a); a = fmaf(hv.y, wa.z, a);
                a = fmaf(hv.z, wbv.x, a); a = fmaf(hv.w, wbv.z, a);
            } else {
                a = fmaf(hv.x, wa.y, a); a = fmaf(hv.y, wa.w, a);
                a = fmaf(hv.z, wbv.y, a); a = fmaf(hv.w, wbv.w, a);
            }
        }
        if (c) {
            const float* o2p = orig + (size_t)(r0 + ray2) * 3;
            const float* e2p = endp + (size_t)(r0 + ray2) * 3;
            float dx = e2p[0] - o2p[0], dy = e2p[1] - o2p[1], dz = e2p[2] - o2p[2];
            a *= sqrtf(dx * dx + dy * dy + dz * dz);
        }
        out[((r0 + ray2) << 1) + c] = a;
    }
}

extern "C" void kernel_launch(void* const* d_in, const int* in_sizes, int n_in,
                              void* d_out, int out_size, void* d_ws, size_t ws_size,
                              hipStream_t stream) {
    const float* orig = (const float*)d_in[0];
    const float* endp = (const float*)d_in[1];
    const int*   hist = (const int*)d_in[2];
    const float* nmin = (const float*)d_in[3];
    const float* next = (const float*)d_in[4];
    const float* emb  = (const float*)d_in[5];
    const float* W1   = (const float*)d_in[6];
    const float* W2   = (const float*)d_in[7];
    const float* W3   = (const float*)d_in[8];
    float* out = (float*)d_out;
    const int n_rays = in_sizes[0] / 3;
    dim3 grid(n_rays / RPB);

    const size_t w1t_bytes = (size_t)64 * 1024 * sizeof(unsigned short);  // 128 KB
    if (ws_size >= w1t_bytes && d_ws != nullptr) {
        unsigned short* W1T = (unsigned short*)d_ws;
        w1t_pre<<<dim3(32), dim3(256), 0, stream>>>(W1, W1T);
        nbvh_kernel<true><<<grid, THREADS, 0, stream>>>(orig, endp, hist, nmin, next,
                                                        emb, W1, W1T, W2, W3, out);
    } else {
        nbvh_kernel<false><<<grid, THREADS, 0, stream>>>(orig, endp, hist, nmin, next,
                                                         emb, W1, nullptr, W2, W3, out);
    }
}